// Round 4
// baseline (9.938 us; speedup 1.0000x reference)
//
#include <hip/hip_runtime.h>

// Problem constants (fixed by the reference).
constexpr int N = 4096;      // IN_FEATURES (reduction axis)
constexpr int F = 16384;     // OUT_DIM
constexpr int TPB = 64;      // one wave per block -> __all() exit vote, no barriers
constexpr int BLOCKS = F / TPB;   // 256 blocks, 1 column per thread
constexpr int W = 32;        // rows per decision window

// SOBOL_RNG[i] == bitreverse8(gray(i)) for BITWIDTH=8 — closed form of the
// gray-code Sobol construction (bijection of 0..255), verified vs reference.
__device__ __forceinline__ int sobol_thresh(int idx) {
    unsigned g = (unsigned)idx & 255u;   // rng_idx % 256
    g ^= g >> 1;                         // gray code
    return (int)(__brev(g) >> 24);       // 8-bit bit reversal
}

// bit = rint((p+1)*128) > SOBOL[idx]; fmaf(p,128,128) == fl(p+1)*128 exactly,
// rintf == jnp.round (half-even). Path validated absmax=0 in rounds 1-3.
__device__ __forceinline__ int bitval(float p, int idx) {
    float s = rintf(fmaf(p, 128.0f, 128.0f));
    return s > (float)sobol_thresh(idx) ? 1 : 0;
}

// Exact early-termination scan (correct for ANY inputs):
//   out[f] = (fp32(acc[f] + cnt[f]) >= 4096),  cnt = # set bits in column f.
//   cnt* = min integer c with fp32(acc + c) >= 4096 (monotone in c).
//   sure-one  if cnt >= cnt*;  sure-zero if cnt + remaining < cnt*.
// Wave exits when all 64 columns are decided; worst case = full scan (exact).
__global__ __launch_bounds__(TPB) void unary_scan(const float* __restrict__ prob,
                                                  const int* __restrict__ idx,
                                                  const float* __restrict__ acc,
                                                  float* __restrict__ out) {
    const int col = blockIdx.x * TPB + threadIdx.x;
    const float* p = prob + col;
    const int*   q = idx + col;

    // ---- issue window-0 loads FIRST (all 64 in flight, one latency wait) ----
    float pv[W];
    int   qv[W];
#pragma unroll
    for (int k = 0; k < W; ++k) {
        pv[k] = p[(size_t)k * F];
        qv[k] = q[(size_t)k * F];
    }

    // ---- cstar fixup overlaps the in-flight loads ----
    const float a = acc[col];
    int cstar = 4096 - (int)a;
    if (cstar < 0) cstar = 0;
    if (cstar > N + 1) cstar = N + 1;
    while (cstar > 0 && a + (float)(cstar - 1) >= 4096.0f) --cstar;
    while (cstar <= N && a + (float)cstar < 4096.0f) ++cstar;
    // cstar in [0, N+1]; N+1 means unreachable -> out 0.

    int cnt = 0;
#pragma unroll
    for (int k = 0; k < W; ++k) cnt += bitval(pv[k], qv[k]);

    int r = W;
    while (true) {
        const int remaining = N - r;
        const bool decided = (cnt >= cstar) | (cnt + remaining < cstar);
        if (__all((int)decided)) break;
        if (r >= N) break;
        // next window: batch-issue loads, then consume
#pragma unroll
        for (int k = 0; k < W; ++k) {
            pv[k] = p[(size_t)(r + k) * F];
            qv[k] = q[(size_t)(r + k) * F];
        }
#pragma unroll
        for (int k = 0; k < W; ++k) cnt += bitval(pv[k], qv[k]);
        r += W;
    }
    out[col] = (cnt >= cstar) ? 1.0f : 0.0f;
}

extern "C" void kernel_launch(void* const* d_in, const int* in_sizes, int n_in,
                              void* d_out, int out_size, void* d_ws, size_t ws_size,
                              hipStream_t stream) {
    // setup_inputs order: st_in_prob[0], accumulator[1], input_bits[2] (UNUSED), rng_idx[3]
    const float* prob = (const float*)d_in[0];
    const float* acc  = (const float*)d_in[1];
    const int*   idx  = (const int*)d_in[3];
    float* out = (float*)d_out;

    unary_scan<<<BLOCKS, TPB, 0, stream>>>(prob, idx, acc, out);
}